// Round 4
// 417.955 us; speedup vs baseline: 1.0373x; 1.0373x over previous
//
#include <hip/hip_runtime.h>
#include <cstdint>
#include <cstddef>

// DeepseekV3 MoE on gfx950.
// R5->R6: (1) GEMM K-loops restructured to T3 "minimum 2-phase": LDS
// double-buffer, STAGE(next-tile) issued BEFORE compute(cur), ONE
// __syncthreads per K-step (its implicit vmcnt(0) drain is covered by the
// ~300cy of ds_read+MFMA between issue and barrier). Previously: stage ->
// barrier-with-drain -> compute -> barrier (2 barriers, zero overlap) ->
// latency-bound at 25% MfmaUtil / 14% HBM / 17% occupancy.
// (2) XCD-aware bijective swizzle on both GEMM grids (896 = 8*112 blocks):
// consecutive work units (8 n-blocks of a tile, consecutive tiles of an
// expert) pin to one XCD -> A-tile + weight-panel reuse moves LLC->L2.
// (3) k_cvt folded into k_router (x row already loaded there); 6 transpose
// launches fused to 3. Launches 13 -> 8.
// Buffer selection in the K-loop is compile-time (unrolled pairs) so the
// compiler can prove gld16 writes don't alias current ds_reads.
// R8 resubmit: rounds 1-3 hit GPUAcquisitionTimeout (no bench ran).

#define T_TOK 2048
#define DIM   1024
#define NEXP  16
#define MAXTILES 80
#define SH_TILES 32
#define GRID_Y (MAXTILES + SH_TILES)
#define NBLK (8 * GRID_Y)        // 896 = 8 XCDs * 112
#define ABASE_SH 10240           // act row where shared-expert rows start

typedef __bf16 bf16x8_t __attribute__((ext_vector_type(8)));
typedef float  f32x4_t  __attribute__((ext_vector_type(4)));
typedef unsigned short ushort8_t __attribute__((ext_vector_type(8)));
typedef unsigned short ushort4_t __attribute__((ext_vector_type(4)));

// ---- workspace layout (bytes) ----
#define OFF_XB     (0UL)            // 4 MB   (dead after k_gateup)
#define OFF_SHGT   (4UL<<20)        // 4 MB   [2048][1024] (dead after k_gateup)
#define OFF_SHUT   (8UL<<20)        // 4 MB
#define OFF_GATET  (12UL<<20)       // 32 MB  [E][F][D] (dead after k_gateup)
#define OFF_UPT    (44UL<<20)       // 32 MB
#define OFF_DOWNT  (76UL<<20)       // 32 MB  [E][D][F]
#define OFF_SHDT   (108UL<<20)      // 4 MB   [1024][2048]
#define OFF_ACT    (112UL<<20)      // 28 MB  (14336 rows x 1024 bf16)
#define OFF_YSLOT  (140UL<<20)      // 20 MB  (10240 rows x 1024 bf16)
#define OFF_PART   (0UL)            // 16 MB  fp32 2 slabs, overlays XB/SHGT/SHUT/GATET-head
#define OFF_CTRL   (160UL<<20)
#define CT_OFFSETS  128
#define CT_NTILES   192
#define CT_TILEEXP  256
#define CT_SLOTTOK  4096
#define CT_TKSLOT   49152
#define CT_TOPKIDX  81920
#define CT_TOPKW    114688

__device__ __forceinline__ unsigned short f2bf(float f) {
  __bf16 h = (__bf16)f;
  return __builtin_bit_cast(unsigned short, h);
}
__device__ __forceinline__ float bf2f(unsigned short u) {
  unsigned int v = ((unsigned int)u) << 16;
  return __builtin_bit_cast(float, v);
}
__device__ __forceinline__ void gld16(const void* g, void* l) {
  __builtin_amdgcn_global_load_lds(
      (const __attribute__((address_space(1))) void*)(g),
      (__attribute__((address_space(3))) void*)(l), 16, 0, 0);
}

// ---- transpose + convert body: src fp32 [R][C] -> dst bf16 [C][R] ----
__device__ __forceinline__ void tbody(const float* __restrict__ src,
                                      unsigned short* __restrict__ dst,
                                      int R, int C) {
  __shared__ unsigned short tile[64 * 68];
  int cT = blockIdx.x * 64, rT = blockIdx.y * 64;
  int t = threadIdx.x;
  int rb = t >> 4, cb = t & 15;
  float f[4][4];
#pragma unroll
  for (int i = 0; i < 4; i++) {
    float4 v = *(const float4*)(src + (long)(rT + 4 * rb + i) * C + cT + 4 * cb);
    f[i][0] = v.x; f[i][1] = v.y; f[i][2] = v.z; f[i][3] = v.w;
  }
#pragma unroll
  for (int j = 0; j < 4; j++) {
    ushort4_t o;
    o[0] = f2bf(f[0][j]); o[1] = f2bf(f[1][j]); o[2] = f2bf(f[2][j]); o[3] = f2bf(f[3][j]);
    int c = 4 * cb + j;
    *(ushort4_t*)&tile[c * 68 + 4 * rb] = o;
  }
  __syncthreads();
#pragma unroll
  for (int p = 0; p < 2; p++) {
    int q = t + 256 * p;
    int c = q >> 3, r0 = (q & 7) * 8;
    ushort4_t lo = *(const ushort4_t*)&tile[c * 68 + r0];
    ushort4_t hi = *(const ushort4_t*)&tile[c * 68 + r0 + 4];
    ushort8_t w8 = {lo[0], lo[1], lo[2], lo[3], hi[0], hi[1], hi[2], hi[3]};
    *(ushort8_t*)(dst + (long)(cT + c) * R + rT + r0) = w8;
  }
}

// generic (used for sh_down): z = batch index
__global__ void k_transpose(const float* __restrict__ src, unsigned short* __restrict__ dst,
                            int R, int C) {
  long b = blockIdx.z;
  tbody(src + b * (long)R * C, dst + b * (long)R * C, R, C);
}

// fused gate/up/down expert-weight transpose: grid (16,16,48), z>>4 selects weight
__global__ void k_transpose3(const float* __restrict__ g, const float* __restrict__ u,
                             const float* __restrict__ d, unsigned short* __restrict__ gT,
                             unsigned short* __restrict__ uT, unsigned short* __restrict__ dT) {
  int z = blockIdx.z;
  int which = z >> 4;
  long b = z & 15;
  const float* s = (which == 0) ? g : (which == 1) ? u : d;
  unsigned short* t = (which == 0) ? gT : (which == 1) ? uT : dT;
  tbody(s + b * 1048576L, t + b * 1048576L, 1024, 1024);
}

// fused shared gate/up transpose: grid (32,16,2)
__global__ void k_transpose_sh(const float* __restrict__ sg, const float* __restrict__ su,
                               unsigned short* __restrict__ gT, unsigned short* __restrict__ uT) {
  const float* s = blockIdx.z ? su : sg;
  unsigned short* t = blockIdx.z ? uT : gT;
  tbody(s, t, 1024, 2048);
}

// ---- router: 1 block per token; also emits xb (bf16 x) ----
__global__ __launch_bounds__(256) void k_router(
    const float* __restrict__ x, const float* __restrict__ rw,
    const float* __restrict__ bias, int* __restrict__ topk_idx,
    float* __restrict__ topk_w, unsigned short* __restrict__ xb) {
  int t = blockIdx.x, tid = threadIdx.x;
  int wv = tid >> 6, lane = tid & 63;
  float4 xv = ((const float4*)(x + (size_t)t * DIM))[tid];
  // fused fp32 -> bf16 conversion of x (replaces k_cvt)
  ushort4_t xo;
  xo[0] = f2bf(xv.x); xo[1] = f2bf(xv.y); xo[2] = f2bf(xv.z); xo[3] = f2bf(xv.w);
  ((ushort4_t*)(xb + (size_t)t * DIM))[tid] = xo;
  float part[NEXP];
#pragma unroll
  for (int e = 0; e < NEXP; e++) {
    float4 wr = ((const float4*)(rw + (size_t)e * DIM))[tid];
    part[e] = xv.x * wr.x + xv.y * wr.y + xv.z * wr.z + xv.w * wr.w;
  }
  __shared__ float wsum_s[4 * NEXP];
#pragma unroll
  for (int e = 0; e < NEXP; e++) {
    float v = part[e];
#pragma unroll
    for (int off = 32; off; off >>= 1) v += __shfl_xor(v, off, 64);
    if (lane == 0) wsum_s[wv * NEXP + e] = v;
  }
  __syncthreads();
  if (tid == 0) {
    float r_sc[NEXP], r_s[NEXP];
#pragma unroll
    for (int e = 0; e < NEXP; e++) {
      float logit = wsum_s[e] + wsum_s[NEXP + e] + wsum_s[2 * NEXP + e] +
                    wsum_s[3 * NEXP + e];
      float sc = 1.f / (1.f + expf(-logit));
      r_sc[e] = sc;
      r_s[e] = sc + bias[e];
    }
    float gs[4];
#pragma unroll
    for (int g = 0; g < 4; g++) {
      float m1 = -1e30f, m2 = -1e30f;
#pragma unroll
      for (int j = 0; j < 4; j++) {
        float v = r_s[g * 4 + j];
        if (v > m1) { m2 = m1; m1 = v; } else if (v > m2) m2 = v;
      }
      gs[g] = m1 + m2;
    }
    int g1 = 0;
    for (int g = 1; g < 4; g++) if (gs[g] > gs[g1]) g1 = g;
    int g2 = -1;
    for (int g = 0; g < 4; g++) { if (g == g1) continue; if (g2 < 0 || gs[g] > gs[g2]) g2 = g; }
    int taken = 0, idx[4];
    float w[4], wsum = 1e-20f;
#pragma unroll
    for (int k = 0; k < 4; k++) {
      float best = -1e30f; int bi = 0;
#pragma unroll
      for (int e2 = 0; e2 < 16; e2++) {
        if (taken & (1 << e2)) continue;
        int g = e2 >> 2;
        float v = (g == g1 || g == g2) ? r_s[e2] : -1.f;
        if (v > best) { best = v; bi = e2; }
      }
      taken |= 1 << bi; idx[k] = bi;
    }
#pragma unroll
    for (int k = 0; k < 4; k++) { w[k] = r_sc[idx[k]]; wsum += w[k]; }
    float sc2 = 2.5f / wsum;
#pragma unroll
    for (int k = 0; k < 4; k++) {
      topk_idx[t * 4 + k] = idx[k];
      topk_w[t * 4 + k] = w[k] * sc2;
    }
  }
}

// ---- route_post: single block, atomic-free count + scan + scatter ----
__global__ __launch_bounds__(256) void k_route_post(
    const int* __restrict__ topk_idx, int* __restrict__ offsets,
    int* __restrict__ tile_expert, int* __restrict__ n_tiles,
    int* __restrict__ slot_token, int* __restrict__ tk_slot) {
  __shared__ int cnt[NEXP][257];
  __shared__ int offs[NEXP], tot[NEXP];
  int tid = threadIdx.x;
  int4 ent[8];
#pragma unroll
  for (int i = 0; i < 8; i++) ent[i] = ((const int4*)topk_idx)[tid * 8 + i];
  int lc[NEXP];
#pragma unroll
  for (int j = 0; j < NEXP; j++) lc[j] = 0;
#pragma unroll
  for (int i = 0; i < 8; i++) {
    int es[4] = {ent[i].x, ent[i].y, ent[i].z, ent[i].w};
#pragma unroll
    for (int k = 0; k < 4; k++)
#pragma unroll
      for (int j = 0; j < NEXP; j++) lc[j] += (es[k] == j) ? 1 : 0;
  }
#pragma unroll
  for (int j = 0; j < NEXP; j++) cnt[j][tid] = lc[j];
  __syncthreads();
  if (tid < NEXP) {
    int base = 0;
    for (int c = 0; c < 256; c += 8) {
      int v[8];
#pragma unroll
      for (int i = 0; i < 8; i++) v[i] = cnt[tid][c + i];
#pragma unroll
      for (int i = 0; i < 8; i++) { cnt[tid][c + i] = base; base += v[i]; }
    }
    tot[tid] = base;
  }
  __syncthreads();
  if (tid == 0) {
    int cum = 0, tt = 0;
    for (int e = 0; e < NEXP; e++) {
      offs[e] = cum;
      offsets[e] = cum;
      int nt = (tot[e] + 127) >> 7;
      for (int i = 0; i < nt; i++) tile_expert[tt++] = e;
      cum += nt << 7;
    }
    n_tiles[0] = tt;
  }
  __syncthreads();
  for (int e = 0; e < NEXP; e++) {
    int s0 = offs[e] + tot[e];
    int s1 = offs[e] + (((tot[e] + 127) >> 7) << 7);
    for (int s = s0 + tid; s < s1; s += 256) slot_token[s] = -1;
  }
  int lcur[NEXP];
#pragma unroll
  for (int j = 0; j < NEXP; j++) lcur[j] = offs[j] + cnt[j][tid];
#pragma unroll
  for (int i = 0; i < 8; i++) {
    int t = tid * 8 + i;
    int es[4] = {ent[i].x, ent[i].y, ent[i].z, ent[i].w};
#pragma unroll
    for (int k = 0; k < 4; k++) {
      int e = es[k], pos = 0;
#pragma unroll
      for (int j = 0; j < NEXP; j++) pos += (e == j) ? lcur[j] : 0;
#pragma unroll
      for (int j = 0; j < NEXP; j++) lcur[j] += (e == j) ? 1 : 0;
      slot_token[pos] = t;
      tk_slot[t * 4 + k] = pos;
    }
  }
}

// ---- fused gate+up+silu GEMM, unified routed+shared, dbuf 2-phase ----
// 1D grid 896 blocks, XCD-swizzled: o -> w=(o&7)*112+(o>>3); bt=w>>3, nx=w&7.
__global__ __launch_bounds__(256, 2) void k_gateup(
    const unsigned short* __restrict__ xb, const unsigned short* __restrict__ gateT,
    const unsigned short* __restrict__ upT, const unsigned short* __restrict__ shGT,
    const unsigned short* __restrict__ shUT, unsigned short* __restrict__ act,
    const int* __restrict__ slot_token, const int* __restrict__ tile_expert,
    const int* __restrict__ n_tiles) {
  int o = blockIdx.x;
  int wk = (o & 7) * GRID_Y + (o >> 3);   // bijective XCD swizzle (896 % 8 == 0)
  int nx = wk & 7, bt = wk >> 3;
  int NT = n_tiles[0];
  bool routed = bt < NT;
  const unsigned short *Bg, *Bu;
  int actbase, tokbase = 0;
  if (routed) {
    int e = tile_expert[bt];
    Bg = gateT + ((size_t)e << 20);
    Bu = upT + ((size_t)e << 20);
    actbase = bt * 128;
  } else {
    int st = bt - NT;
    if (st >= SH_TILES) return;
    int se = st >> 4, tt = st & 15;
    Bg = shGT + ((size_t)se << 20);
    Bu = shUT + ((size_t)se << 20);
    actbase = ABASE_SH + se * T_TOK + tt * 128;
    tokbase = tt * 128;
  }
  int n0 = nx * 128;

  // [2 bufs][A | Bg | Bu], 8 KB tiles -> 48 KB total
  __shared__ unsigned short lds[2 * 3 * 128 * 32];

  int tid = threadIdx.x;
  int w = tid >> 6, L = tid & 63;
  int c0 = w * 128 + L, c1 = c0 + 64;
  int ar0 = c0 >> 2, ar1 = c1 >> 2;
  int ch0 = (c0 & 3) ^ (ar0 & 3), ch1 = (c1 & 3) ^ (ar1 & 3);
  long arow0, arow1;
  if (routed) {
    int t0 = slot_token[bt * 128 + ar0]; if (t0 < 0) t0 = 0;
    int t1 = slot_token[bt * 128 + ar1]; if (t1 < 0) t1 = 0;
    arow0 = t0; arow1 = t1;
  } else {
    arow0 = tokbase + ar0; arow1 = tokbase + ar1;
  }
  const char* aA = (const char*)(xb + arow0 * 1024) + ch0 * 16;
  const char* aB = (const char*)(xb + arow1 * 1024) + ch1 * 16;
  const char* gA = (const char*)(Bg + (size_t)(n0 + ar0) * 1024) + ch0 * 16;
  const char* gB = (const char*)(Bg + (size_t)(n0 + ar1) * 1024) + ch1 * 16;
  const char* uA = (const char*)(Bu + (size_t)(n0 + ar0) * 1024) + ch0 * 16;
  const char* uB = (const char*)(Bu + (size_t)(n0 + ar1) * 1024) + ch1 * 16;
  // byte offsets within a buffer: A at 0, Bg at 8192, Bu at 16384
  const int a0o = w * 2048, a1o = w * 2048 + 1024;
  const int g0o = 8192 + w * 2048, g1o = 8192 + w * 2048 + 1024;
  const int u0o = 16384 + w * 2048, u1o = 16384 + w * 2048 + 1024;

  f32x4_t accg[4][4], accu[4][4];
#pragma unroll
  for (int i = 0; i < 4; i++)
#pragma unroll
    for (int j = 0; j < 4; j++) {
      accg[i][j] = f32x4_t{0.f, 0.f, 0.f, 0.f};
      accu[i][j] = f32x4_t{0.f, 0.f, 0.f, 0.f};
    }

  int mb = (w >> 1) * 64, nb = (w & 1) * 64;
  int lr = L & 15, quad = L >> 4;
  int sw = ((quad ^ (lr & 3)) << 3);

#define GU_STAGE(BOFF)                                                       \
  { char* bp = (char*)lds + (BOFF);                                          \
    gld16(aA, bp + a0o); gld16(aB, bp + a1o);                                \
    gld16(gA, bp + g0o); gld16(gB, bp + g1o);                                \
    gld16(uA, bp + u0o); gld16(uB, bp + u1o);                                \
    aA += 64; aB += 64; gA += 64; gB += 64; uA += 64; uB += 64; }

#define GU_COMPUTE(UOFF)                                                     \
  { const unsigned short* pA = lds + (UOFF);                                 \
    const unsigned short* pG = pA + 4096;                                    \
    const unsigned short* pU = pA + 8192;                                    \
    bf16x8_t af[4], bg[4], bu[4];                                            \
    _Pragma("unroll")                                                        \
    for (int i = 0; i < 4; i++) af[i] = *(const bf16x8_t*)(pA + (mb + 16 * i + lr) * 32 + sw); \
    _Pragma("unroll")                                                        \
    for (int i = 0; i < 4; i++) bg[i] = *(const bf16x8_t*)(pG + (nb + 16 * i + lr) * 32 + sw); \
    _Pragma("unroll")                                                        \
    for (int i = 0; i < 4; i++) bu[i] = *(const bf16x8_t*)(pU + (nb + 16 * i + lr) * 32 + sw); \
    _Pragma("unroll")                                                        \
    for (int i = 0; i < 4; i++)                                              \
      _Pragma("unroll")                                                      \
      for (int j = 0; j < 4; j++) {                                          \
        accg[i][j] = __builtin_amdgcn_mfma_f32_16x16x32_bf16(af[i], bg[j], accg[i][j], 0, 0, 0); \
        accu[i][j] = __builtin_amdgcn_mfma_f32_16x16x32_bf16(af[i], bu[j], accu[i][j], 0, 0, 0); \
      } }

  // T3 minimum 2-phase: stage(next) BEFORE compute(cur); ONE barrier/K-step.
  GU_STAGE(0);
  __syncthreads();
#pragma unroll 1
  for (int p = 0; p < 15; ++p) {
    GU_STAGE(24576); GU_COMPUTE(0);     __syncthreads();
    GU_STAGE(0);     GU_COMPUTE(12288); __syncthreads();
  }
  GU_STAGE(24576); GU_COMPUTE(0); __syncthreads();
  GU_COMPUTE(12288);
#undef GU_STAGE
#undef GU_COMPUTE

#pragma unroll
  for (int i = 0; i < 4; i++) {
    int rowb = actbase + mb + 16 * i + quad * 4;
#pragma unroll
    for (int j = 0; j < 4; j++) {
      int col = n0 + nb + 16 * j + lr;
#pragma unroll
      for (int r = 0; r < 4; r++) {
        float h = accg[i][j][r];
        float u = accu[i][j][r];
        float a = h / (1.f + __expf(-h)) * u;
        act[(size_t)(rowb + r) * 1024 + col] = f2bf(a);
      }
    }
  }
}

// ---- down GEMM, unified routed+shared, dbuf 2-phase ----
__global__ __launch_bounds__(256, 2) void k_down(
    const unsigned short* __restrict__ act, const unsigned short* __restrict__ downT,
    const unsigned short* __restrict__ shDT, unsigned short* __restrict__ yslot,
    float* __restrict__ part, const int* __restrict__ tile_expert,
    const int* __restrict__ n_tiles) {
  int o = blockIdx.x;
  int wk = (o & 7) * GRID_Y + (o >> 3);
  int nx = wk & 7, bt = wk >> 3;
  int NT = n_tiles[0];
  bool routed = bt < NT;
  const unsigned short* B;
  size_t bstride;
  int abase, obase, se = 0;
  if (routed) {
    int e = tile_expert[bt];
    B = downT + ((size_t)e << 20);
    bstride = 1024;
    abase = bt * 128;
    obase = bt * 128;
  } else {
    int st = bt - NT;
    if (st >= SH_TILES) return;
    se = st >> 4;
    int tt = st & 15;
    B = shDT + se * 1024;
    bstride = 2048;
    abase = ABASE_SH + se * T_TOK + tt * 128;
    obase = tt * 128;
  }
  int n0 = nx * 128;

  // [2 bufs][A | B], 8 KB tiles -> 32 KB total
  __shared__ unsigned short lds[2 * 2 * 128 * 32];

  int tid = threadIdx.x;
  int w = tid >> 6, L = tid & 63;
  int c0 = w * 128 + L, c1 = c0 + 64;
  int ar0 = c0 >> 2, ar1 = c1 >> 2;
  int ch0 = (c0 & 3) ^ (ar0 & 3), ch1 = (c1 & 3) ^ (ar1 & 3);
  const char* aA = (const char*)(act + (size_t)(abase + ar0) * 1024) + ch0 * 16;
  const char* aB = (const char*)(act + (size_t)(abase + ar1) * 1024) + ch1 * 16;
  const char* bA = (const char*)(B + (size_t)(n0 + ar0) * bstride) + ch0 * 16;
  const char* bB = (const char*)(B + (size_t)(n0 + ar1) * bstride) + ch1 * 16;
  const int a0o = w * 2048, a1o = w * 2048 + 1024;
  const int b0o = 8192 + w * 2048, b1o = 8192 + w * 2048 + 1024;

  f32x4_t acc[4][4];
#pragma unroll
  for (int i = 0; i < 4; i++)
#pragma unroll
    for (int j = 0; j < 4; j++) acc[i][j] = f32x4_t{0.f, 0.f, 0.f, 0.f};

  int mb = (w >> 1) * 64, nb = (w & 1) * 64;
  int lr = L & 15, quad = L >> 4;
  int sw = ((quad ^ (lr & 3)) << 3);

#define DN_STAGE(BOFF)                                                       \
  { char* bp = (char*)lds + (BOFF);                                          \
    gld16(aA, bp + a0o); gld16(aB, bp + a1o);                                \
    gld16(bA, bp + b0o); gld16(bB, bp + b1o);                                \
    aA += 64; aB += 64; bA += 64; bB += 64; }

#define DN_COMPUTE(UOFF)                                                     \
  { const unsigned short* pA = lds + (UOFF);                                 \
    const unsigned short* pB = pA + 4096;                                    \
    bf16x8_t af[4], bb[4];                                                   \
    _Pragma("unroll")                                                        \
    for (int i = 0; i < 4; i++) af[i] = *(const bf16x8_t*)(pA + (mb + 16 * i + lr) * 32 + sw); \
    _Pragma("unroll")                                                        \
    for (int i = 0; i < 4; i++) bb[i] = *(const bf16x8_t*)(pB + (nb + 16 * i + lr) * 32 + sw); \
    _Pragma("unroll")                                                        \
    for (int i = 0; i < 4; i++)                                              \
      _Pragma("unroll")                                                      \
      for (int j = 0; j < 4; j++)                                            \
        acc[i][j] = __builtin_amdgcn_mfma_f32_16x16x32_bf16(af[i], bb[j], acc[i][j], 0, 0, 0); }

  DN_STAGE(0);
  __syncthreads();
#pragma unroll 1
  for (int p = 0; p < 15; ++p) {
    DN_STAGE(16384); DN_COMPUTE(0);    __syncthreads();
    DN_STAGE(0);     DN_COMPUTE(8192); __syncthreads();
  }
  DN_STAGE(16384); DN_COMPUTE(0); __syncthreads();
  DN_COMPUTE(8192);
#undef DN_STAGE
#undef DN_COMPUTE

#pragma unroll
  for (int i = 0; i < 4; i++) {
    int rowb = obase + mb + 16 * i + quad * 4;
#pragma unroll
    for (int j = 0; j < 4; j++) {
      int col = n0 + nb + 16 * j + lr;
#pragma unroll
      for (int r = 0; r < 4; r++) {
        float v = acc[i][j][r];
        if (routed) yslot[(size_t)(rowb + r) * 1024 + col] = f2bf(v);
        else part[(size_t)se * (T_TOK * 1024) + (size_t)(rowb + r) * 1024 + col] = v;
      }
    }
  }
}

// ---- final gather: out = part0 + part1 + sum_k w_k * yslot[slot_k] ----
__global__ void k_gather(float* __restrict__ out, const float* __restrict__ partial,
                         const unsigned short* __restrict__ yslot,
                         const int* __restrict__ tk_slot, const float* __restrict__ topk_w) {
  int t = blockIdx.x, tid = threadIdx.x;
  int4 sl = ((const int4*)tk_slot)[t];
  float4 wv = ((const float4*)topk_w)[t];
  int d = 4 * tid;
  float4 p0 = *(const float4*)(partial + (size_t)t * 1024 + d);
  float4 p1 = *(const float4*)(partial + (size_t)(T_TOK * 1024) + (size_t)t * 1024 + d);
  float4 o = {p0.x + p1.x, p0.y + p1.y, p0.z + p1.z, p0.w + p1.w};
  const int s[4] = {sl.x, sl.y, sl.z, sl.w};
  const float wk[4] = {wv.x, wv.y, wv.z, wv.w};
#pragma unroll
  for (int k = 0; k < 4; k++) {
    ushort4_t y = *(const ushort4_t*)(yslot + (size_t)s[k] * 1024 + d);
    o.x += wk[k] * bf2f(y[0]);
    o.y += wk[k] * bf2f(y[1]);
    o.z += wk[k] * bf2f(y[2]);
    o.w += wk[k] * bf2f(y[3]);
  }
  *(float4*)(out + (size_t)t * 1024 + d) = o;
}

extern "C" void kernel_launch(void* const* d_in, const int* in_sizes, int n_in,
                              void* d_out, int out_size, void* d_ws, size_t ws_size,
                              hipStream_t stream) {
  const float* x = (const float*)d_in[0];
  const float* rw = (const float*)d_in[1];
  const float* bias = (const float*)d_in[2];
  const float* gw = (const float*)d_in[3];
  const float* uw = (const float*)d_in[4];
  const float* dw = (const float*)d_in[5];
  const float* sg = (const float*)d_in[6];
  const float* su = (const float*)d_in[7];
  const float* sd = (const float*)d_in[8];
  float* out = (float*)d_out;
  char* ws = (char*)d_ws;

  unsigned short* xb    = (unsigned short*)(ws + OFF_XB);
  unsigned short* shGT  = (unsigned short*)(ws + OFF_SHGT);
  unsigned short* shUT  = (unsigned short*)(ws + OFF_SHUT);
  unsigned short* gateT = (unsigned short*)(ws + OFF_GATET);
  unsigned short* upT   = (unsigned short*)(ws + OFF_UPT);
  unsigned short* downT = (unsigned short*)(ws + OFF_DOWNT);
  unsigned short* shDT  = (unsigned short*)(ws + OFF_SHDT);
  unsigned short* act   = (unsigned short*)(ws + OFF_ACT);
  unsigned short* yslot = (unsigned short*)(ws + OFF_YSLOT);
  float*          part  = (float*)(ws + OFF_PART);   // overlays xb/shGT/shUT/gateT-head
  char* ctrl = ws + OFF_CTRL;
  int* offsets_    = (int*)(ctrl + CT_OFFSETS);
  int* n_tiles     = (int*)(ctrl + CT_NTILES);
  int* tile_expert = (int*)(ctrl + CT_TILEEXP);
  int* slot_token  = (int*)(ctrl + CT_SLOTTOK);
  int* tk_slot     = (int*)(ctrl + CT_TKSLOT);
  int* topk_idx    = (int*)(ctrl + CT_TOPKIDX);
  float* topk_w    = (float*)(ctrl + CT_TOPKW);

  k_transpose3<<<dim3(16, 16, 48), 256, 0, stream>>>(gw, uw, dw, gateT, upT, downT);
  k_transpose_sh<<<dim3(32, 16, 2), 256, 0, stream>>>(sg, su, shGT, shUT);
  k_transpose<<<dim3(16, 32, 1), 256, 0, stream>>>(sd, shDT, 2048, 1024);
  k_router<<<2048, 256, 0, stream>>>(x, rw, bias, topk_idx, topk_w, xb);
  k_route_post<<<1, 256, 0, stream>>>(topk_idx, offsets_, tile_expert, n_tiles,
                                      slot_token, tk_slot);
  // fused gate+up+silu for routed + shared "experts" (XCD-swizzled 1D grid)
  k_gateup<<<NBLK, 256, 0, stream>>>(xb, gateT, upT, shGT, shUT, act,
                                     slot_token, tile_expert, n_tiles);
  // down for routed (-> yslot bf16) + shared (-> fp32 partial slabs)
  k_down<<<NBLK, 256, 0, stream>>>(act, downT, shDT, yslot, part,
                                   tile_expert, n_tiles);
  // out = p0+p1 + weighted routed
  k_gather<<<2048, 256, 0, stream>>>(out, part, yslot, tk_slot, topk_w);
}